// Round 3
// baseline (1710.335 us; speedup 1.0000x reference)
//
#include <hip/hip_runtime.h>
#include <math.h>

namespace {

constexpr int kB = 32;
constexpr int kN = 19;
constexpr int kT = 2048;
constexpr int kD = 128;

// Single-wave workgroups: 6 tiles x 10 lanes = 60 active lanes.
// Round-3: double-buffered async staging (global_load_lds, counted vmcnt(8))
// replaces the load->reg->ds_write path and its per-chunk vmcnt(0) drain.
constexpr int TILES = 6;           // (b,t) tiles per single-wave block
constexpr int TPT   = 10;          // threads per tile: upper-tri of 4x4 grid of 5x5
constexpr int BDIM  = 64;          // ONE wave
constexpr int KC    = 16;          // k-chunk depth (floats per staging round)
constexpr int CHUNK_F4 = TILES * kN * (KC / 4); // 456 float4 per chunk
constexpr int STAGE_F4 = CHUNK_F4;              // one stage buffer = 7,296 B

constexpr int RPAD  = 21;          // odd Gram-row pitch -> conflict-light LDS
constexpr int TSTR  = 400;         // 19*21=399 -> 400

constexpr int NT    = kB * kT;                    // 65536 tiles total
constexpr int NGRID = (NT + TILES - 1) / TILES;   // 10923 blocks (last has 4 valid tiles)

constexpr float kTempInv = 10.0f;  // 1/TEMPERATURE
constexpr float kThresh  = 1e-4f;

// async global->LDS, 16 B/lane. Dest is wave-uniform base + lane*16 (linear!),
// so the stage layout is forced to float4-index q = iter*64 + lane.
#define GLOAD16(GP, LP, OFF)                                            \
    __builtin_amdgcn_global_load_lds(                                   \
        (__attribute__((address_space(1))) void*)(GP),                  \
        (__attribute__((address_space(3))) void*)(LP), 16, (OFF), 0)

// counted waitcnt: N loads may stay in flight across the wait (T4).
// sched_barrier(0) fences compiler reordering past the asm (guide rule #18).
#define WAITV(N)                                                        \
    do { asm volatile("s_waitcnt vmcnt(" #N ")" ::: "memory");          \
         __builtin_amdgcn_sched_barrier(0); } while (0)

// Issue one chunk's 8 wave-loads (456 float4 -> 7 full + 1 eight-lane ragged).
// OFFB = chunk byte offset (kc advance = 64 B/chunk), folded into the literal
// offset: field -> zero per-chunk address arithmetic.
template <int OFFB>
__device__ __forceinline__ void issue_chunk(const float* const (&gsrc)[8],
                                            float4* dst, int lane)
{
#pragma unroll
    for (int i = 0; i < 7; ++i)
        GLOAD16(gsrc[i], dst + i * 64, OFFB);
    if (lane < 8)                      // q = 448+lane < 456; exec never 0
        GLOAD16(gsrc[7], dst + 7 * 64, OFFB);
}

// (64,2): VGPR cap 256 -> ~130-150 live regs, no spill (round 1's (64,4)
// forced the 64-reg tier and 1.9 GB of scratch writes). LDS 14,592 B ->
// 11 blocks/CU; each an independent single-wave pipeline.
__global__ __launch_bounds__(BDIM, 2)
void fused_graph_kernel(const float* __restrict__ feat, float* __restrict__ out)
{
    // Stage double-buffer (2 x 456 float4 = 14,592 B); after the k-loop the
    // same memory is reused as the per-tile Gram/prob region (10,080 B).
    __shared__ float4 stage[2][STAGE_F4];
    float* smem = (float*)stage;

    const int lane = threadIdx.x;
    int tl = lane / TPT;               // tile-local index 0..5 (6 for idle lanes)
    const int sub = lane - tl * TPT;   // 0..9 -> (bi,bj), bi<=bj
    const bool laneValid = (tl < TILES);
    if (!laneValid) tl = TILES - 1;    // lanes 60..63 shadow tile 5; writes guarded

    const int bi    = (sub >= 4) + (sub >= 7) + (sub >= 9);
    const int start = bi * 4 - (bi * (bi - 1)) / 2;
    const int bj    = bi + (sub - start);

    const int gt0 = blockIdx.x * TILES;                      // global tile base = b*T + t
    const int vT  = (NT - gt0 < TILES) ? (NT - gt0) : TILES; // valid tiles (tail block)

    // clamped row indices for my 5x5 block (row 19 -> 18; garbage acc never used)
    int ar[5], bc[5];
#pragma unroll
    for (int r = 0; r < 5; ++r) { ar[r] = bi * 5 + r; if (ar[r] > kN - 1) ar[r] = kN - 1; }
#pragma unroll
    for (int c = 0; c < 5; ++c) { bc[c] = bj * 5 + c; if (bc[c] > kN - 1) bc[c] = kN - 1; }

    float acc[5][5];
#pragma unroll
    for (int r = 0; r < 5; ++r)
#pragma unroll
        for (int c = 0; c < 5; ++c) acc[r][c] = 0.f;

    // ---- hoisted staging addresses: one per sub-load slot, affine in kc ----
    // stage float4 q holds (n = (q>>2)/6, t = (q>>2)%6, d4 = q&3); global src
    // for q at chunk kc is gsrc[i] + kc*4 B-scaled (handled by offset:/bump).
    const float* gsrc[8];
#pragma unroll
    for (int i = 0; i < 8; ++i) {
        int q = i * 64 + lane;
        if (q > CHUNK_F4 - 1) q = CHUNK_F4 - 1;   // masked-off lanes: keep addr valid
        const int r  = q >> 2;
        const int d4 = q & 3;
        const int t  = r % TILES;
        const int n  = r / TILES;
        int g = gt0 + t;
        if (g > NT - 1) g = NT - 1;               // tail block: clamp (dup reads, safe)
        const size_t flat = (((size_t)(g >> 11) * kN + n) << 11) + (size_t)(g & (kT - 1));
        gsrc[i] = feat + (flat << 7) + (d4 << 2);
    }

    // ---- 5x5 register-blocked Gram from one staged chunk ----
    auto compute = [&](const float4* sb) {
#pragma unroll
        for (int s0 = 0; s0 < 4; ++s0) {
            const int s = (s0 + sub) & 3;   // stagger to spread LDS banks
            float4 ra[5], cb[5];
#pragma unroll
            for (int r = 0; r < 5; ++r)
                ra[r] = sb[(ar[r] * TILES + tl) * 4 + s];
            if (bi == bj) {
#pragma unroll
                for (int c = 0; c < 5; ++c) cb[c] = ra[c];
            } else {
#pragma unroll
                for (int c = 0; c < 5; ++c)
                    cb[c] = sb[(bc[c] * TILES + tl) * 4 + s];
            }
#pragma unroll
            for (int r = 0; r < 5; ++r)
#pragma unroll
                for (int c = 0; c < 5; ++c) {
                    acc[r][c] = fmaf(ra[r].x, cb[c].x, acc[r][c]);
                    acc[r][c] = fmaf(ra[r].y, cb[c].y, acc[r][c]);
                    acc[r][c] = fmaf(ra[r].z, cb[c].z, acc[r][c]);
                    acc[r][c] = fmaf(ra[r].w, cb[c].w, acc[r][c]);
                }
        }
    };

    // ============ Phase A: software-pipelined k-loop (8 chunks of KC=16) ============
    // Steady state: issue chunk c+1 into the other buffer, wait vmcnt(8)
    // (= chunk c landed, c+1 still in flight), compute chunk c. No barrier,
    // no vmcnt(0) until the last chunk. Single wave -> no races possible.
    issue_chunk<0>(gsrc, stage[0], lane);            // c0
    issue_chunk<64>(gsrc, stage[1], lane);           // c1
    WAITV(8);
    compute(stage[0]);                               // c0
#pragma unroll 1
    for (int it = 0; it < 3; ++it) {                 // (c2..c6 issue, c1..c5 compute)
#pragma unroll
        for (int i = 0; i < 8; ++i) gsrc[i] += 32;   // advance 2 chunks = 128 B
        issue_chunk<0>(gsrc, stage[0], lane);        // c2+2it
        WAITV(8);
        compute(stage[1]);                           // c1+2it
        issue_chunk<64>(gsrc, stage[1], lane);       // c3+2it
        WAITV(8);
        compute(stage[0]);                           // c2+2it
    }
    WAITV(0);
    compute(stage[1]);                               // c7

    // ============ Phase A2: scatter Gram into LDS (overwrites staging) with mirror ============
    {
        float* g = &smem[tl * TSTR];
#pragma unroll
        for (int r = 0; r < 5; ++r) {
            const int i = bi * 5 + r;
#pragma unroll
            for (int c = 0; c < 5; ++c) {
                const int j = bj * 5 + c;
                if (laneValid && i < kN && j < kN) {
                    g[i * RPAD + j] = acc[r][c];
                    if (i != j) g[j * RPAD + i] = acc[r][c];
                }
            }
        }
    }
    __syncthreads();

    // ============ Phase B1: inverse norms from Gram diagonal ============
    float* sInv = &smem[TILES * TSTR];
    for (int q = lane; q < TILES * kN; q += BDIM) {
        const int tt = q / kN;
        const int i  = q - tt * kN;
        const float nrm = sqrtf(smem[tt * TSTR + i * RPAD + i]);
        sInv[tt * 20 + i] = 1.0f / fmaxf(nrm, 1e-12f);
    }
    __syncthreads();

    // ============ Phase B2: per-row softmax + exact top-3 + threshold (in place) ============
    for (int q = lane; q < TILES * kN; q += BDIM) {
        const int tt = q / kN;
        const int i  = q - tt * kN;
        float* row = &smem[tt * TSTR + i * RPAD];
        const float* invp = &sInv[tt * 20];
        const float si = invp[i] * kTempInv;

        float l[kN];
        float m = -3.0e38f;
#pragma unroll
        for (int j = 0; j < kN; ++j) {
            const float g = row[j] * si * invp[j];
            l[j] = g;
            m = fmaxf(m, g);
        }
        float ssum = 0.f;
#pragma unroll
        for (int j = 0; j < kN; ++j) {
            const float e = __expf(l[j] - m);
            l[j] = e;
            ssum += e;
        }
        const float rs = 1.0f / ssum;
#pragma unroll
        for (int j = 0; j < kN; ++j) l[j] *= rs;

        // top-3 with lax.top_k tie semantics (strict > keeps lowest index on ties)
        int k1 = 0; float v1 = -1.f;
#pragma unroll
        for (int j = 0; j < kN; ++j) if (l[j] > v1) { v1 = l[j]; k1 = j; }
        int k2 = -1; float v2 = -1.f;
#pragma unroll
        for (int j = 0; j < kN; ++j) if (j != k1 && l[j] > v2) { v2 = l[j]; k2 = j; }
        int k3 = -1; float v3 = -1.f;
#pragma unroll
        for (int j = 0; j < kN; ++j) if (j != k1 && j != k2 && l[j] > v3) { v3 = l[j]; k3 = j; }

#pragma unroll
        for (int j = 0; j < kN; ++j) {
            const float p = l[j];
            const bool keep = (j == k1 || j == k2 || j == k3) && (p > kThresh);
            row[j] = keep ? p : 0.f;
        }
    }
    __syncthreads();

    // ============ Phase C: symmetrize + contiguous coalesced store ============
    float* ob = out + (size_t)gt0 * (kN * kN);
    const int qMax = vT * (kN * kN);   // tail block stores only valid tiles
    for (int q = lane; q < qMax; q += BDIM) {
        const int tt = q / (kN * kN);
        const int r  = q - tt * (kN * kN);
        const int i  = r / kN;
        const int j  = r - i * kN;
        const float v = 0.5f * (smem[tt * TSTR + i * RPAD + j] +
                                smem[tt * TSTR + j * RPAD + i]);
        ob[q] = v;   // contiguous span per block
    }
}

} // namespace

extern "C" void kernel_launch(void* const* d_in, const int* in_sizes, int n_in,
                              void* d_out, int out_size, void* d_ws, size_t ws_size,
                              hipStream_t stream)
{
    const float* feat = (const float*)d_in[0];
    float* out = (float*)d_out;
    dim3 grid(NGRID);    // 10923 single-wave blocks
    dim3 block(BDIM);    // 64 threads = 1 wave
    hipLaunchKernelGGL(fused_graph_kernel, grid, block, 0, stream, feat, out);
}